// Round 9
// baseline (2968.898 us; speedup 1.0000x reference)
//
#include <hip/hip_runtime.h>

#define NPTS 8192
#define NSAMP 1024
#define NBATCH 8
#define KNB 32
#define NPROD 8
#define NCONS 120

typedef float f32x2 __attribute__((ext_vector_type(2)));
typedef unsigned long long u64;

// Packed f32 ops — IEEE rn per half, identical results to scalar v_add/v_mul.
__device__ __forceinline__ f32x2 pk_add(f32x2 a, f32x2 b) {
  f32x2 d; asm("v_pk_add_f32 %0, %1, %2" : "=v"(d) : "v"(a), "v"(b)); return d;
}
__device__ __forceinline__ f32x2 pk_mul(f32x2 a, f32x2 b) {
  f32x2 d; asm("v_pk_mul_f32 %0, %1, %2" : "=v"(d) : "v"(a), "v"(b)); return d;
}

// Single-dep-chain DPP reduce rounds (old = own value, safe for min/max).
#define DPP_FMAX_ROUND(v, CTRL)                                                        \
  do {                                                                                 \
    int _b = __float_as_int(v);                                                        \
    int _p = __builtin_amdgcn_update_dpp(_b, _b, CTRL, 0xF, 0xF, false);               \
    (v) = fmaxf((v), __int_as_float(_p));                                              \
  } while (0)

#define DPP_FMIN_ROUND(v, CTRL)                                                        \
  do {                                                                                 \
    int _b = __float_as_int(v);                                                        \
    int _p = __builtin_amdgcn_update_dpp(_b, _b, CTRL, 0xF, 0xF, false);               \
    (v) = fminf((v), __int_as_float(_p));                                              \
  } while (0)

#define DPP_UMIN_ROUND(v, CTRL)                                                        \
  do {                                                                                 \
    unsigned _p = (unsigned)__builtin_amdgcn_update_dpp((int)(v), (int)(v), CTRL,      \
                                                        0xF, 0xF, false);              \
    if (_p < (v)) (v) = _p;                                                            \
  } while (0)

// u64 key min round — used for the 3 cross-wave rounds.
#define DPP_MIN_ROUND(k, CTRL)                                                         \
  do {                                                                                 \
    unsigned _lo = (unsigned)(k), _hi = (unsigned)((k) >> 32);                         \
    unsigned _plo = (unsigned)__builtin_amdgcn_update_dpp((int)_lo, (int)_lo, CTRL,    \
                                                          0xF, 0xF, false);            \
    unsigned _phi = (unsigned)__builtin_amdgcn_update_dpp((int)_hi, (int)_hi, CTRL,    \
                                                          0xF, 0xF, false);            \
    u64 _ok = (((u64)_phi) << 32) | _plo;                                              \
    if (_ok < (k)) (k) = _ok;                                                          \
  } while (0)

// Exact-match squared distance: ((dx*dx + dy*dy) + dz*dz), rn ops, no FMA.
__device__ __forceinline__ float sqdist_rn(float px, float py, float pz,
                                           float qx, float qy, float qz) {
  float dx = px - qx, dy = py - qy, dz = pz - qz;
  return __fadd_rn(__fadd_rn(__fmul_rn(dx, dx), __fmul_rn(dy, dy)), __fmul_rn(dz, dz));
}

// ---------------------------------------------------------------------------
// Fused kernel. Blocks 0..7: FPS producers (one per batch, R7 structure:
// x-sorted slabs + wave-level pruning). Blocks 8..127: persistent consumers;
// each 512-thread block = two 256-thread teams, each team does ball-query
// (indices kept in LDS) + attention mean + 3-layer MLP + max-pool for one
// sample. Producers publish progress prog[b] (device-scope) every 8 steps;
// consumers acquire-poll. 128 blocks x ~99KB LDS = 1 block/CU -> all blocks
// co-resident by capacity; no dispatch-order assumptions between waiters and
// producers of DIFFERENT blocks beyond capacity (grid << 256 CUs).
// Exact semantics preserved everywhere (see per-phase comments in earlier
// rounds); absmax has been 0.0 since R1.
// ---------------------------------------------------------------------------
__global__ __launch_bounds__(512, 1) void fused_kernel(
    const float* __restrict__ xyz, const float* __restrict__ pts,
    const float* __restrict__ att,
    const float* __restrict__ w0, const float* __restrict__ b0,
    const float* __restrict__ w1, const float* __restrict__ b1,
    const float* __restrict__ w2, const float* __restrict__ b2,
    float* __restrict__ out_newxyz, float* __restrict__ out_np,
    float* __restrict__ att_out, unsigned* __restrict__ prog) {
  __shared__ __align__(16) char smem_raw[98304];
  __shared__ u64 wkeys[2][8];
  __shared__ int sidxs[2][KNB];

  const int tid = threadIdx.x;

  if (blockIdx.x < NPROD) {
    // =====================  PRODUCER: FPS  =====================
    u64* sbuf = reinterpret_cast<u64*>(smem_raw);
    float* cds = reinterpret_cast<float*>(smem_raw);  // [n]={x,y,z}, stride 12B

    const int b = blockIdx.x;
    const int lane = tid & 63;
    const int wv = tid >> 6;
    const float* xb = xyz + (size_t)b * 3 * NPTS;

    // phase 0: sort keys (x >= 0 so u32 bit order == float order)
    for (int j = 0; j < 16; j++) {
      int n = tid + j * 512;
      float x = xb[n];
      sbuf[n] = (((u64)__float_as_uint(x)) << 32) | (u64)n;
    }
    __syncthreads();

    // bitonic sort ascending, 8192 u64 keys in LDS
    for (unsigned k = 2; k <= (unsigned)NPTS; k <<= 1) {
      for (unsigned jm = k >> 1; jm > 0; jm >>= 1) {
        for (int p = 0; p < 16; p++) {
          unsigned i = (unsigned)tid + (unsigned)p * 512u;
          unsigned ixj = i ^ jm;
          if (ixj > i) {
            u64 a = sbuf[i], c = sbuf[ixj];
            bool up = ((i & k) == 0);
            if ((a > c) == up) { sbuf[i] = c; sbuf[ixj] = a; }
          }
        }
        __syncthreads();
      }
    }

    // phase 1: thread t takes sorted slots [t*16, t*16+16)
    f32x2 X2[8], Y2[8], Z2[8], D2[8];
    unsigned idxp[8];
    float txmin = 1e30f, txmax = -1e30f;
#pragma unroll
    for (int j = 0; j < 8; j++) {
      u64 k0 = sbuf[tid * 16 + 2 * j];
      u64 k1 = sbuf[tid * 16 + 2 * j + 1];
      unsigned n0 = (unsigned)k0 & 8191u, n1 = (unsigned)k1 & 8191u;
      float x0 = __uint_as_float((unsigned)(k0 >> 32));
      float x1 = __uint_as_float((unsigned)(k1 >> 32));
      X2[j].x = x0; X2[j].y = x1;
      Y2[j].x = xb[NPTS + n0];     Y2[j].y = xb[NPTS + n1];
      Z2[j].x = xb[2 * NPTS + n0]; Z2[j].y = xb[2 * NPTS + n1];
      D2[j].x = 1e10f;             D2[j].y = 1e10f;
      idxp[j] = n0 | (n1 << 16);
      txmin = fminf(txmin, fminf(x0, x1));
      txmax = fmaxf(txmax, fmaxf(x0, x1));
    }
    DPP_FMIN_ROUND(txmin, 0x111); DPP_FMIN_ROUND(txmin, 0x112);
    DPP_FMIN_ROUND(txmin, 0x114); DPP_FMIN_ROUND(txmin, 0x118);
    DPP_FMIN_ROUND(txmin, 0x142); DPP_FMIN_ROUND(txmin, 0x143);
    DPP_FMAX_ROUND(txmax, 0x111); DPP_FMAX_ROUND(txmax, 0x112);
    DPP_FMAX_ROUND(txmax, 0x114); DPP_FMAX_ROUND(txmax, 0x118);
    DPP_FMAX_ROUND(txmax, 0x142); DPP_FMAX_ROUND(txmax, 0x143);
    const float xlo = __int_as_float(__builtin_amdgcn_readlane(__float_as_int(txmin), 63));
    const float xhi = __int_as_float(__builtin_amdgcn_readlane(__float_as_int(txmax), 63));
    __syncthreads();

    // phase 2: overlay cds (coords by ORIGINAL index)
#pragma unroll
    for (int j = 0; j < 8; j++) {
      unsigned n0 = idxp[j] & 0xFFFFu, n1 = idxp[j] >> 16;
      cds[n0 * 3 + 0] = X2[j].x; cds[n0 * 3 + 1] = Y2[j].x; cds[n0 * 3 + 2] = Z2[j].x;
      cds[n1 * 3 + 0] = X2[j].y; cds[n1 * 3 + 1] = Y2[j].y; cds[n1 * 3 + 2] = Z2[j].y;
    }
    __syncthreads();

    float sx = cds[0], sy = cds[1], sz = cds[2];
    float bv_cache = 1e10f;
    u64 key_cache = ~0ull;

    for (int t = 0; t < NSAMP; t++) {
      // store selection t's coords (exact copies of input coords)
      if (tid == 0) {
        out_newxyz[(b * 3 + 0) * NSAMP + t] = sx;
        out_newxyz[(b * 3 + 1) * NSAMP + t] = sy;
        out_newxyz[(b * 3 + 2) * NSAMP + t] = sz;
      }

      // wave-uniform skip test (rn-monotone lower bound proof)
      float gap = fmaxf(fmaxf(xlo - sx, sx - xhi), 0.0f);
      float lb = __fmul_rn(gap, gap);

      if (lb < bv_cache) {
        f32x2 nqx, nqy, nqz;
        nqx.x = -sx; nqx.y = -sx;
        nqy.x = -sy; nqy.y = -sy;
        nqz.x = -sz; nqz.y = -sz;
        float bvx = -1.0f, bvy = -1.0f;
#pragma unroll
        for (int j = 0; j < 8; j++) {
          f32x2 dx = pk_add(X2[j], nqx);
          f32x2 dy = pk_add(Y2[j], nqy);
          f32x2 dz = pk_add(Z2[j], nqz);
          f32x2 dd = pk_add(pk_add(pk_mul(dx, dx), pk_mul(dy, dy)), pk_mul(dz, dz));
          float m0 = fminf(D2[j].x, dd.x);
          float m1 = fminf(D2[j].y, dd.y);
          D2[j].x = m0;
          D2[j].y = m1;
          bvx = fmaxf(bvx, m0);
          bvy = fmaxf(bvy, m1);
        }
        float bv = fmaxf(bvx, bvy);

        DPP_FMAX_ROUND(bv, 0x111);
        DPP_FMAX_ROUND(bv, 0x112);
        DPP_FMAX_ROUND(bv, 0x114);
        DPP_FMAX_ROUND(bv, 0x118);
        DPP_FMAX_ROUND(bv, 0x142);
        DPP_FMAX_ROUND(bv, 0x143);
        float wval = __int_as_float(__builtin_amdgcn_readlane(__float_as_int(bv), 63));

        // rescan (descending) for == wval: exact smallest-orig-index tie-break
        unsigned cand = 0xFFFFFFFFu;
#pragma unroll
        for (int j = 0; j < 8; j++) {
          unsigned n0 = idxp[j] & 0xFFFFu, n1 = idxp[j] >> 16;
          if (D2[j].y == wval && n1 < cand) cand = n1;
          if (D2[j].x == wval && n0 < cand) cand = n0;
        }
        DPP_UMIN_ROUND(cand, 0x111);
        DPP_UMIN_ROUND(cand, 0x112);
        DPP_UMIN_ROUND(cand, 0x114);
        DPP_UMIN_ROUND(cand, 0x118);
        DPP_UMIN_ROUND(cand, 0x142);
        DPP_UMIN_ROUND(cand, 0x143);

        key_cache = (((u64)(~__float_as_uint(wval))) << 32) | (u64)cand;
        bv_cache = wval;
        if (lane == 63) wkeys[t & 1][wv] = key_cache;
      } else {
        if (lane == 63) wkeys[t & 1][wv] = key_cache;
      }
      __syncthreads();
      u64 k8 = wkeys[t & 1][lane & 7];
      DPP_MIN_ROUND(k8, 0xB1);   // quad_perm ^1
      DPP_MIN_ROUND(k8, 0x4E);   // quad_perm ^2
      DPP_MIN_ROUND(k8, 0x141);  // row_half_mirror
      unsigned wid = (unsigned)__builtin_amdgcn_readfirstlane((int)(unsigned)k8);

      sx = cds[wid * 3 + 0];
      sy = cds[wid * 3 + 1];
      sz = cds[wid * 3 + 2];

      // publish progress every 8 steps (selections 0..t are stored)
      if ((t & 7) == 7 && tid == 0) {
        __threadfence();
        atomicExch(&prog[b], (unsigned)(t + 1));
      }
    }
  } else {
    // =====================  CONSUMER: ballq + MLP  =====================
    float* smemF = reinterpret_cast<float*>(smem_raw);
    const int tm = tid >> 8;     // team 0/1
    const int t = tid & 255;     // thread-in-team
    float* feat = smemF + tm * 6784;          // [67][32]
    float* h0s = feat + 2144;                 // [64][36]
    float* h1s = h0s + 2304;                  // [64][36]

    for (int p = (int)blockIdx.x - NPROD; p < (NBATCH * NSAMP) / 2; p += NCONS) {
      const int gA = 2 * p;
      const int b = gA >> 10;
      const int sA = gA & 1023;
      // wait for producer b to have published selections 0..sA+1
      if (tid == 0) {
        unsigned need = (unsigned)(sA + 2);
        while (atomicAdd(&prog[b], 0u) < need) __builtin_amdgcn_s_sleep(64);
        __threadfence();
      }
      __syncthreads();

      const int g = gA + tm;
      const int s = sA + tm;
      const float* xb = xyz + (size_t)b * 3 * NPTS;

      // ---- ball query by first wave of each team; indices stay in LDS ----
      if (t < 64) {
        const int lane = t;
        float qx = out_newxyz[(b * 3 + 0) * NSAMP + s];
        float qy = out_newxyz[(b * 3 + 1) * NSAMP + s];
        float qz = out_newxyz[(b * 3 + 2) * NSAMP + s];
        int have = 0;
        int firstn = 0;
        for (int c = 0; c < NPTS / 64; c++) {
          int n = c * 64 + lane;
          float dd = sqdist_rn(xb[n], xb[NPTS + n], xb[2 * NPTS + n], qx, qy, qz);
          bool inb = (dd <= 0.04f);
          unsigned long long m = __ballot(inb);
          if (have == 0 && m != 0ull) firstn = c * 64 + __builtin_ctzll(m);
          int pre = __popcll(m & ((1ull << lane) - 1ull));
          if (inb && (have + pre) < KNB) sidxs[tm][have + pre] = n;
          have += __popcll(m);
          if (have >= KNB) break;
        }
        if (have > KNB) have = KNB;
        if (lane < KNB && lane >= have) sidxs[tm][lane] = firstn;  // pad

        float av = 0.0f;
        if (lane < KNB) av = att[(size_t)b * NPTS + sidxs[tm][lane]];
#pragma unroll
        for (int m = 1; m < 64; m <<= 1) av += __shfl_xor(av, m, 64);
        if (lane == 0) att_out[g] = av * 0.03125f;
      }
      __syncthreads();

      // ---- gather ----
      {
        int k = t & 31, rg = t >> 5;
        int n = sidxs[tm][k];
        const float* pb = pts + (size_t)b * 64 * NPTS;
        for (int r = rg; r < 67; r += 8) {
          float v;
          if (r < 3)
            v = xyz[((size_t)b * 3 + r) * NPTS + n] -
                out_newxyz[(b * 3 + r) * NSAMP + s];
          else
            v = pb[(size_t)(r - 3) * NPTS + n];
          feat[r * 32 + k] = v;
        }
      }
      __syncthreads();

      const int kq = t & 7;
      const int og = t >> 3;

      // ---- layer 0: 67 -> 64 ----
      {
        float a0[8];
        float bu = b0[2 * og], bw = b0[2 * og + 1];
        a0[0] = a0[1] = a0[2] = a0[3] = bu;
        a0[4] = a0[5] = a0[6] = a0[7] = bw;
        const float* wr0 = w0 + (2 * og) * 67;
        const float* wr1 = wr0 + 67;
        for (int c = 0; c < 67; c++) {
          float4 f = *(const float4*)&feat[c * 32 + kq * 4];
          float u = wr0[c], v = wr1[c];
          a0[0] = fmaf(u, f.x, a0[0]); a0[1] = fmaf(u, f.y, a0[1]);
          a0[2] = fmaf(u, f.z, a0[2]); a0[3] = fmaf(u, f.w, a0[3]);
          a0[4] = fmaf(v, f.x, a0[4]); a0[5] = fmaf(v, f.y, a0[5]);
          a0[6] = fmaf(v, f.z, a0[6]); a0[7] = fmaf(v, f.w, a0[7]);
        }
        float4 r0, r1;
        r0.x = fmaxf(a0[0], 0.f); r0.y = fmaxf(a0[1], 0.f);
        r0.z = fmaxf(a0[2], 0.f); r0.w = fmaxf(a0[3], 0.f);
        r1.x = fmaxf(a0[4], 0.f); r1.y = fmaxf(a0[5], 0.f);
        r1.z = fmaxf(a0[6], 0.f); r1.w = fmaxf(a0[7], 0.f);
        *(float4*)&h0s[(2 * og) * 36 + kq * 4] = r0;
        *(float4*)&h0s[(2 * og + 1) * 36 + kq * 4] = r1;
      }
      __syncthreads();

      // ---- layer 1: 64 -> 64 ----
      {
        float a1[8];
        float bu = b1[2 * og], bw = b1[2 * og + 1];
        a1[0] = a1[1] = a1[2] = a1[3] = bu;
        a1[4] = a1[5] = a1[6] = a1[7] = bw;
        const float* wr0 = w1 + (2 * og) * 64;
        const float* wr1 = wr0 + 64;
        for (int c = 0; c < 64; c++) {
          float4 f = *(const float4*)&h0s[c * 36 + kq * 4];
          float u = wr0[c], v = wr1[c];
          a1[0] = fmaf(u, f.x, a1[0]); a1[1] = fmaf(u, f.y, a1[1]);
          a1[2] = fmaf(u, f.z, a1[2]); a1[3] = fmaf(u, f.w, a1[3]);
          a1[4] = fmaf(v, f.x, a1[4]); a1[5] = fmaf(v, f.y, a1[5]);
          a1[6] = fmaf(v, f.z, a1[6]); a1[7] = fmaf(v, f.w, a1[7]);
        }
        float4 r0, r1;
        r0.x = fmaxf(a1[0], 0.f); r0.y = fmaxf(a1[1], 0.f);
        r0.z = fmaxf(a1[2], 0.f); r0.w = fmaxf(a1[3], 0.f);
        r1.x = fmaxf(a1[4], 0.f); r1.y = fmaxf(a1[5], 0.f);
        r1.z = fmaxf(a1[6], 0.f); r1.w = fmaxf(a1[7], 0.f);
        *(float4*)&h1s[(2 * og) * 36 + kq * 4] = r0;
        *(float4*)&h1s[(2 * og + 1) * 36 + kq * 4] = r1;
      }
      __syncthreads();

      // ---- layer 2: 64 -> 128, max over k ----
      {
        const int kq2 = t & 3;
        const int og2 = t >> 2;
        float a2[16];
        float bu = b2[2 * og2], bw = b2[2 * og2 + 1];
#pragma unroll
        for (int i = 0; i < 8; i++) { a2[i] = bu; a2[8 + i] = bw; }
        const float* wr0 = w2 + (2 * og2) * 64;
        const float* wr1 = wr0 + 64;
        for (int c = 0; c < 64; c++) {
          float4 fA = *(const float4*)&h1s[c * 36 + kq2 * 8];
          float4 fB = *(const float4*)&h1s[c * 36 + kq2 * 8 + 4];
          float u = wr0[c], v = wr1[c];
          a2[0] = fmaf(u, fA.x, a2[0]);  a2[1] = fmaf(u, fA.y, a2[1]);
          a2[2] = fmaf(u, fA.z, a2[2]);  a2[3] = fmaf(u, fA.w, a2[3]);
          a2[4] = fmaf(u, fB.x, a2[4]);  a2[5] = fmaf(u, fB.y, a2[5]);
          a2[6] = fmaf(u, fB.z, a2[6]);  a2[7] = fmaf(u, fB.w, a2[7]);
          a2[8] = fmaf(v, fA.x, a2[8]);  a2[9] = fmaf(v, fA.y, a2[9]);
          a2[10] = fmaf(v, fA.z, a2[10]); a2[11] = fmaf(v, fA.w, a2[11]);
          a2[12] = fmaf(v, fB.x, a2[12]); a2[13] = fmaf(v, fB.y, a2[13]);
          a2[14] = fmaf(v, fB.z, a2[14]); a2[15] = fmaf(v, fB.w, a2[15]);
        }
        float m0 = a2[0], m1 = a2[8];
#pragma unroll
        for (int i = 1; i < 8; i++) { m0 = fmaxf(m0, a2[i]); m1 = fmaxf(m1, a2[8 + i]); }
        m0 = fmaxf(m0, 0.f);
        m1 = fmaxf(m1, 0.f);
        m0 = fmaxf(m0, __shfl_xor(m0, 1, 64));
        m0 = fmaxf(m0, __shfl_xor(m0, 2, 64));
        m1 = fmaxf(m1, __shfl_xor(m1, 1, 64));
        m1 = fmaxf(m1, __shfl_xor(m1, 2, 64));
        if (kq2 == 0) {
          out_np[((size_t)b * 128 + 2 * og2) * NSAMP + s] = m0;
          out_np[((size_t)b * 128 + 2 * og2 + 1) * NSAMP + s] = m1;
        }
      }
      __syncthreads();  // protect LDS (sidxs/feat) before next iteration
    }
  }
}

extern "C" void kernel_launch(void* const* d_in, const int* in_sizes, int n_in,
                              void* d_out, int out_size, void* d_ws, size_t ws_size,
                              hipStream_t stream) {
  (void)in_sizes; (void)n_in; (void)out_size; (void)ws_size;
  const float* xyz = (const float*)d_in[0];
  const float* pts = (const float*)d_in[1];
  const float* att = (const float*)d_in[2];
  const float* w0 = (const float*)d_in[3];
  const float* b0 = (const float*)d_in[4];
  const float* w1 = (const float*)d_in[5];
  const float* b1 = (const float*)d_in[6];
  const float* w2 = (const float*)d_in[7];
  const float* b2 = (const float*)d_in[8];

  float* out = (float*)d_out;
  float* out_newxyz = out;                                            // (B,3,S)
  float* out_newpts = out + NBATCH * 3 * NSAMP;                       // (B,128,S)
  float* out_att = out + NBATCH * 3 * NSAMP + NBATCH * 128 * NSAMP;   // (B,1,S)
  unsigned* prog = (unsigned*)d_ws;  // 8 progress counters

  hipMemsetAsync(prog, 0, NBATCH * sizeof(unsigned), stream);
  fused_kernel<<<NPROD + NCONS, 512, 0, stream>>>(
      xyz, pts, att, w0, b0, w1, b1, w2, b2,
      out_newxyz, out_newpts, out_att, prog);
}

// Round 10
// 1573.383 us; speedup vs baseline: 1.8870x; 1.8870x over previous
//
#include <hip/hip_runtime.h>

#define NPTS 8192
#define NSAMP 1024
#define NBATCH 8
#define KNB 32

typedef float f32x2 __attribute__((ext_vector_type(2)));
typedef unsigned long long u64;

// Packed f32 ops — IEEE rn per half, identical results to scalar v_add/v_mul.
__device__ __forceinline__ f32x2 pk_add(f32x2 a, f32x2 b) {
  f32x2 d; asm("v_pk_add_f32 %0, %1, %2" : "=v"(d) : "v"(a), "v"(b)); return d;
}
__device__ __forceinline__ f32x2 pk_mul(f32x2 a, f32x2 b) {
  f32x2 d; asm("v_pk_mul_f32 %0, %1, %2" : "=v"(d) : "v"(a), "v"(b)); return d;
}

// Single-dep-chain DPP reduce rounds (old = own value, safe for min/max).
#define DPP_FMAX_ROUND(v, CTRL)                                                        \
  do {                                                                                 \
    int _b = __float_as_int(v);                                                        \
    int _p = __builtin_amdgcn_update_dpp(_b, _b, CTRL, 0xF, 0xF, false);               \
    (v) = fmaxf((v), __int_as_float(_p));                                              \
  } while (0)

#define DPP_FMIN_ROUND(v, CTRL)                                                        \
  do {                                                                                 \
    int _b = __float_as_int(v);                                                        \
    int _p = __builtin_amdgcn_update_dpp(_b, _b, CTRL, 0xF, 0xF, false);               \
    (v) = fminf((v), __int_as_float(_p));                                              \
  } while (0)

// u64 key min round — used for the 2 cross-wave rounds.
#define DPP_MIN_ROUND(k, CTRL)                                                         \
  do {                                                                                 \
    unsigned _lo = (unsigned)(k), _hi = (unsigned)((k) >> 32);                         \
    unsigned _plo = (unsigned)__builtin_amdgcn_update_dpp((int)_lo, (int)_lo, CTRL,    \
                                                          0xF, 0xF, false);            \
    unsigned _phi = (unsigned)__builtin_amdgcn_update_dpp((int)_hi, (int)_hi, CTRL,    \
                                                          0xF, 0xF, false);            \
    u64 _ok = (((u64)_phi) << 32) | _plo;                                              \
    if (_ok < (k)) (k) = _ok;                                                          \
  } while (0)

// Exact-match squared distance: ((dx*dx + dy*dy) + dz*dz), rn ops, no FMA.
__device__ __forceinline__ float sqdist_rn(float px, float py, float pz,
                                           float qx, float qy, float qz) {
  float dx = px - qx, dy = py - qy, dz = pz - qz;
  return __fadd_rn(__fadd_rn(__fmul_rn(dx, dx), __fmul_rn(dy, dy)), __fmul_rn(dz, dz));
}

// ---------------------------------------------------------------------------
// Kernel 1: farthest point sampling, 4-wave variant. One block per batch,
// 256 threads (4 waves, 1/SIMD), 32 points/thread (16 f32x2 pairs), x-sorted
// (bitonic prologue) so each wave owns a contiguous x-slab of 2048 points.
// Per step (active wave):
//   skip test (gap^2 >= wave max D, rn-monotone proof) -> else:
//   update (packed math) -> [6-DPP value-max chain || rescan vs local max ->
//   cand(min orig idx)] -> readlane(63) wval -> ballot(bvl==wval) -> SALU
//   min over tying lanes' cand -> scalar u64 key.
//   lane0 publishes -> ONE barrier -> 2 u64 DPP rounds over 4 slots ->
//   readfirstlane -> coords via broadcast ds_reads.
// Exact semantics: min over keys == argmax by (dist desc, index asc) ==
// jnp.argmax first-occurrence; p + (-q) == p - q bitwise; no FMA contraction.
// ---------------------------------------------------------------------------
__global__ __launch_bounds__(256) void fps_kernel(const float* __restrict__ xyz,
                                                  float* __restrict__ out_newxyz) {
  // 96 KB region: first used as u64 sort buffer (64 KB), then as cds[] coords.
  __shared__ __align__(16) char smem_raw[NPTS * 3 * 4];
  u64* sbuf = reinterpret_cast<u64*>(smem_raw);
  float* cds = reinterpret_cast<float*>(smem_raw);  // [n]={x,y,z}, stride 12B
  __shared__ u64 wkeys[2][4];

  const int b = blockIdx.x;
  const int tid = threadIdx.x;
  const int lane = tid & 63;
  const int wv = tid >> 6;
  const float* xb = xyz + (size_t)b * 3 * NPTS;

  // ---- phase 0: build sort keys (x >= 0 so u32 bit order == float order) ----
  for (int j = 0; j < 32; j++) {
    int n = tid + j * 256;
    float x = xb[n];
    sbuf[n] = (((u64)__float_as_uint(x)) << 32) | (u64)n;
  }
  __syncthreads();

  // ---- bitonic sort ascending, 8192 u64 keys in LDS ----
  for (unsigned k = 2; k <= (unsigned)NPTS; k <<= 1) {
    for (unsigned jm = k >> 1; jm > 0; jm >>= 1) {
      for (int p = 0; p < 32; p++) {
        unsigned i = (unsigned)tid + (unsigned)p * 256u;
        unsigned ixj = i ^ jm;
        if (ixj > i) {
          u64 a = sbuf[i], c = sbuf[ixj];
          bool up = ((i & k) == 0);
          if ((a > c) == up) { sbuf[i] = c; sbuf[ixj] = a; }
        }
      }
      __syncthreads();
    }
  }

  // ---- phase 1: thread t takes sorted slots [t*32, t*32+32): 16 pairs ----
  f32x2 X2[16], Y2[16], Z2[16], D2[16];
  unsigned idxp[16];  // packed original indices: lo16 = .x slot, hi16 = .y slot
  float txmin = 1e30f, txmax = -1e30f;
#pragma unroll
  for (int j = 0; j < 16; j++) {
    u64 k0 = sbuf[tid * 32 + 2 * j];
    u64 k1 = sbuf[tid * 32 + 2 * j + 1];
    unsigned n0 = (unsigned)k0 & 8191u, n1 = (unsigned)k1 & 8191u;
    float x0 = __uint_as_float((unsigned)(k0 >> 32));
    float x1 = __uint_as_float((unsigned)(k1 >> 32));
    X2[j].x = x0; X2[j].y = x1;
    Y2[j].x = xb[NPTS + n0];     Y2[j].y = xb[NPTS + n1];
    Z2[j].x = xb[2 * NPTS + n0]; Z2[j].y = xb[2 * NPTS + n1];
    D2[j].x = 1e10f;             D2[j].y = 1e10f;
    idxp[j] = n0 | (n1 << 16);
    txmin = fminf(txmin, fminf(x0, x1));
    txmax = fmaxf(txmax, fmaxf(x0, x1));
  }
  // wave x-bounds from actual loaded values (sort bugs could only hurt speed)
  DPP_FMIN_ROUND(txmin, 0x111); DPP_FMIN_ROUND(txmin, 0x112);
  DPP_FMIN_ROUND(txmin, 0x114); DPP_FMIN_ROUND(txmin, 0x118);
  DPP_FMIN_ROUND(txmin, 0x142); DPP_FMIN_ROUND(txmin, 0x143);
  DPP_FMAX_ROUND(txmax, 0x111); DPP_FMAX_ROUND(txmax, 0x112);
  DPP_FMAX_ROUND(txmax, 0x114); DPP_FMAX_ROUND(txmax, 0x118);
  DPP_FMAX_ROUND(txmax, 0x142); DPP_FMAX_ROUND(txmax, 0x143);
  const float xlo = __int_as_float(__builtin_amdgcn_readlane(__float_as_int(txmin), 63));
  const float xhi = __int_as_float(__builtin_amdgcn_readlane(__float_as_int(txmax), 63));
  __syncthreads();  // done reading sbuf

  // ---- phase 2: overlay cds (coords by ORIGINAL index) ----
#pragma unroll
  for (int j = 0; j < 16; j++) {
    unsigned n0 = idxp[j] & 0xFFFFu, n1 = idxp[j] >> 16;
    cds[n0 * 3 + 0] = X2[j].x; cds[n0 * 3 + 1] = Y2[j].x; cds[n0 * 3 + 2] = Z2[j].x;
    cds[n1 * 3 + 0] = X2[j].y; cds[n1 * 3 + 1] = Y2[j].y; cds[n1 * 3 + 2] = Z2[j].y;
  }
  __syncthreads();

  // selection 0 = point 0
  float sx = cds[0], sy = cds[1], sz = cds[2];
  unsigned c0i = 0, c1i = 0, c2i = 0, c3i = 0;  // per-thread selection stash
  float bv_cache = 1e10f;  // wave max D (wave-uniform)
  u64 key_cache = ~0ull;   // wave's published key (wave-uniform)

  for (int t = 0; t < NSAMP; t++) {
    // ---- wave-uniform skip test (rn-monotone lower bound) ----
    float gap = fmaxf(fmaxf(xlo - sx, sx - xhi), 0.0f);
    float lb = __fmul_rn(gap, gap);

    if (lb < bv_cache) {
      // ---- full path: distance update (packed math) ----
      f32x2 nqx, nqy, nqz;
      nqx.x = -sx; nqx.y = -sx;
      nqy.x = -sy; nqy.y = -sy;
      nqz.x = -sz; nqz.y = -sz;
      float bvx = -1.0f, bvy = -1.0f;
#pragma unroll
      for (int j = 0; j < 16; j++) {
        f32x2 dx = pk_add(X2[j], nqx);
        f32x2 dy = pk_add(Y2[j], nqy);
        f32x2 dz = pk_add(Z2[j], nqz);
        f32x2 dd = pk_add(pk_add(pk_mul(dx, dx), pk_mul(dy, dy)), pk_mul(dz, dz));
        float m0 = fminf(D2[j].x, dd.x);
        float m1 = fminf(D2[j].y, dd.y);
        D2[j].x = m0;
        D2[j].y = m1;
        bvx = fmaxf(bvx, m0);
        bvy = fmaxf(bvy, m1);
      }
      const float bvl = fmaxf(bvx, bvy);  // thread-local max

      // ---- wave value-max chain (6 DPP rounds on a copy) ----
      float bvr = bvl;
      DPP_FMAX_ROUND(bvr, 0x111);
      DPP_FMAX_ROUND(bvr, 0x112);
      DPP_FMAX_ROUND(bvr, 0x114);
      DPP_FMAX_ROUND(bvr, 0x118);
      DPP_FMAX_ROUND(bvr, 0x142);
      DPP_FMAX_ROUND(bvr, 0x143);

      // ---- rescan vs bvl (independent of the DPP chain -> co-scheduled) ----
      unsigned cand = 0xFFFFFFFFu;
#pragma unroll
      for (int j = 0; j < 16; j++) {
        unsigned n0 = idxp[j] & 0xFFFFu, n1 = idxp[j] >> 16;
        if (D2[j].y == bvl && n1 < cand) cand = n1;
        if (D2[j].x == bvl && n0 < cand) cand = n0;
      }

      float wval = __int_as_float(__builtin_amdgcn_readlane(__float_as_int(bvr), 63));

      // ---- winner index: ballot + SALU min-loop over tying lanes ----
      unsigned long long mask = __ballot(bvl == wval);
      unsigned cm = 0xFFFFFFFFu;
      while (mask) {
        int l = __builtin_ctzll(mask);
        unsigned c = (unsigned)__builtin_amdgcn_readlane((int)cand, l);
        cm = c < cm ? c : cm;
        mask &= mask - 1;
      }

      key_cache = (((u64)(~__float_as_uint(wval))) << 32) | (u64)cm;
      bv_cache = wval;
    }
    // (skip path: key_cache/bv_cache unchanged — provably identical state)

    const int par = t & 1;
    if (lane == 0) wkeys[par][wv] = key_cache;
    __syncthreads();
    u64 k4 = wkeys[par][lane & 3];
    DPP_MIN_ROUND(k4, 0xB1);  // quad_perm [1,0,3,2]  (^1)
    DPP_MIN_ROUND(k4, 0x4E);  // quad_perm [2,3,0,1]  (^2)
    unsigned wid = (unsigned)__builtin_amdgcn_readfirstlane((int)(unsigned)k4);

    // stash: selection (t+1) = wid  (selection 0 preset above)
    if (t + 1 == tid) c0i = wid;
    if (t + 1 == tid + 256) c1i = wid;
    if (t + 1 == tid + 512) c2i = wid;
    if (t + 1 == tid + 768) c3i = wid;

    // winner coords from LDS (uniform addr -> broadcast)
    sx = cds[wid * 3 + 0];
    sy = cds[wid * 3 + 1];
    sz = cds[wid * 3 + 2];
  }

  // epilogue: thread tid writes new_xyz columns tid, tid+256, tid+512, tid+768
  {
    unsigned ci[4] = {c0i, c1i, c2i, c3i};
#pragma unroll
    for (int q = 0; q < 4; q++) {
      float ax = cds[ci[q] * 3 + 0], ay = cds[ci[q] * 3 + 1], az = cds[ci[q] * 3 + 2];
      out_newxyz[(b * 3 + 0) * NSAMP + q * 256 + tid] = ax;
      out_newxyz[(b * 3 + 1) * NSAMP + q * 256 + tid] = ay;
      out_newxyz[(b * 3 + 2) * NSAMP + q * 256 + tid] = az;
    }
  }
}

// ---------------------------------------------------------------------------
// Kernel 2: ball query + attention mean. One wave per (b,s). Scans points in
// ascending index order in chunks of 64, collects the first K in-radius
// indices (ballot + prefix popcount), pads with the first hit.
// ---------------------------------------------------------------------------
__global__ __launch_bounds__(256) void ballq_kernel(const float* __restrict__ xyz,
                                                    const float* __restrict__ att,
                                                    const float* __restrict__ newxyz,
                                                    int* __restrict__ idx_out,
                                                    float* __restrict__ att_out) {
  __shared__ int rowbuf[4][KNB];
  const int wv = threadIdx.x >> 6;
  const int lane = threadIdx.x & 63;
  const int g = blockIdx.x * 4 + wv;  // b*NSAMP + s
  const int b = g >> 10;
  const int s = g & 1023;
  const float* xb = xyz + (size_t)b * 3 * NPTS;

  float qx = newxyz[(b * 3 + 0) * NSAMP + s];
  float qy = newxyz[(b * 3 + 1) * NSAMP + s];
  float qz = newxyz[(b * 3 + 2) * NSAMP + s];

  int have = 0;
  int firstn = 0;
  for (int c = 0; c < NPTS / 64; c++) {
    int n = c * 64 + lane;
    float dd = sqdist_rn(xb[n], xb[NPTS + n], xb[2 * NPTS + n], qx, qy, qz);
    bool inb = (dd <= 0.04f);
    unsigned long long m = __ballot(inb);
    if (have == 0 && m != 0ull) firstn = c * 64 + __builtin_ctzll(m);
    int pre = __popcll(m & ((1ull << lane) - 1ull));
    if (inb && (have + pre) < KNB) rowbuf[wv][have + pre] = n;
    have += __popcll(m);
    if (have >= KNB) break;
  }
  if (have > KNB) have = KNB;
  if (lane < KNB && lane >= have) rowbuf[wv][lane] = firstn;  // pad

  float av = 0.0f;
  if (lane < KNB) {
    int myidx = rowbuf[wv][lane];
    idx_out[(size_t)g * KNB + lane] = myidx;
    av = att[(size_t)b * NPTS + myidx];
  }
#pragma unroll
  for (int m = 1; m < 64; m <<= 1) av += __shfl_xor(av, m, 64);
  if (lane == 0) att_out[g] = av * 0.03125f;  // mean over K=32 (exact /32)
}

// ---------------------------------------------------------------------------
// Kernel 3: gather features + 3-layer MLP + max over K. One 256-thread block
// per (b,s). feat [67][32] and h [64][36] (padded stride) in LDS; weights
// streamed from global (L1/L2 broadcast). f32 fmaf throughout.
// ---------------------------------------------------------------------------
__global__ __launch_bounds__(256) void mlp_kernel(
    const float* __restrict__ xyz, const float* __restrict__ pts,
    const float* __restrict__ newxyz, const int* __restrict__ idx,
    const float* __restrict__ w0, const float* __restrict__ b0,
    const float* __restrict__ w1, const float* __restrict__ b1,
    const float* __restrict__ w2, const float* __restrict__ b2,
    float* __restrict__ out_np) {
  const int g = blockIdx.x;
  const int b = g >> 10;
  const int s = g & 1023;
  const int t = threadIdx.x;

  __shared__ __align__(16) float feat[67 * 32];
  __shared__ __align__(16) float h0s[64 * 36];
  __shared__ __align__(16) float h1s[64 * 36];
  __shared__ int sidx[KNB];

  if (t < KNB) sidx[t] = idx[(size_t)g * KNB + t];
  __syncthreads();

  // gather: rows 0..2 = g_norm (xyz - query), rows 3..66 = point features
  {
    int k = t & 31, rg = t >> 5;
    int n = sidx[k];
    const float* pb = pts + (size_t)b * 64 * NPTS;
    for (int r = rg; r < 67; r += 8) {
      float v;
      if (r < 3)
        v = xyz[((size_t)b * 3 + r) * NPTS + n] - newxyz[(b * 3 + r) * NSAMP + s];
      else
        v = pb[(size_t)(r - 3) * NPTS + n];
      feat[r * 32 + k] = v;
    }
  }
  __syncthreads();

  const int kq = t & 7;   // k block = 4*kq .. +4
  const int og = t >> 3;  // o = 2*og, 2*og+1

  // ---- layer 0: 67 -> 64 ----
  {
    float a0[8];
    float bu = b0[2 * og], bw = b0[2 * og + 1];
    a0[0] = a0[1] = a0[2] = a0[3] = bu;
    a0[4] = a0[5] = a0[6] = a0[7] = bw;
    const float* wr0 = w0 + (2 * og) * 67;
    const float* wr1 = wr0 + 67;
    for (int c = 0; c < 67; c++) {
      float4 f = *(const float4*)&feat[c * 32 + kq * 4];
      float u = wr0[c], v = wr1[c];
      a0[0] = fmaf(u, f.x, a0[0]); a0[1] = fmaf(u, f.y, a0[1]);
      a0[2] = fmaf(u, f.z, a0[2]); a0[3] = fmaf(u, f.w, a0[3]);
      a0[4] = fmaf(v, f.x, a0[4]); a0[5] = fmaf(v, f.y, a0[5]);
      a0[6] = fmaf(v, f.z, a0[6]); a0[7] = fmaf(v, f.w, a0[7]);
    }
    float4 r0, r1;
    r0.x = fmaxf(a0[0], 0.f); r0.y = fmaxf(a0[1], 0.f);
    r0.z = fmaxf(a0[2], 0.f); r0.w = fmaxf(a0[3], 0.f);
    r1.x = fmaxf(a0[4], 0.f); r1.y = fmaxf(a0[5], 0.f);
    r1.z = fmaxf(a0[6], 0.f); r1.w = fmaxf(a0[7], 0.f);
    *(float4*)&h0s[(2 * og) * 36 + kq * 4] = r0;
    *(float4*)&h0s[(2 * og + 1) * 36 + kq * 4] = r1;
  }
  __syncthreads();

  // ---- layer 1: 64 -> 64 ----
  {
    float a1[8];
    float bu = b1[2 * og], bw = b1[2 * og + 1];
    a1[0] = a1[1] = a1[2] = a1[3] = bu;
    a1[4] = a1[5] = a1[6] = a1[7] = bw;
    const float* wr0 = w1 + (2 * og) * 64;
    const float* wr1 = wr0 + 64;
    for (int c = 0; c < 64; c++) {
      float4 f = *(const float4*)&h0s[c * 36 + kq * 4];
      float u = wr0[c], v = wr1[c];
      a1[0] = fmaf(u, f.x, a1[0]); a1[1] = fmaf(u, f.y, a1[1]);
      a1[2] = fmaf(u, f.z, a1[2]); a1[3] = fmaf(u, f.w, a1[3]);
      a1[4] = fmaf(v, f.x, a1[4]); a1[5] = fmaf(v, f.y, a1[5]);
      a1[6] = fmaf(v, f.z, a1[6]); a1[7] = fmaf(v, f.w, a1[7]);
    }
    float4 r0, r1;
    r0.x = fmaxf(a1[0], 0.f); r0.y = fmaxf(a1[1], 0.f);
    r0.z = fmaxf(a1[2], 0.f); r0.w = fmaxf(a1[3], 0.f);
    r1.x = fmaxf(a1[4], 0.f); r1.y = fmaxf(a1[5], 0.f);
    r1.z = fmaxf(a1[6], 0.f); r1.w = fmaxf(a1[7], 0.f);
    *(float4*)&h1s[(2 * og) * 36 + kq * 4] = r0;
    *(float4*)&h1s[(2 * og + 1) * 36 + kq * 4] = r1;
  }
  __syncthreads();

  // ---- layer 2: 64 -> 128, then max over k ----
  {
    const int kq2 = t & 3;   // k block = 8*kq2 .. +8
    const int og2 = t >> 2;  // o = 2*og2, 2*og2+1
    float a2[16];
    float bu = b2[2 * og2], bw = b2[2 * og2 + 1];
#pragma unroll
    for (int i = 0; i < 8; i++) { a2[i] = bu; a2[8 + i] = bw; }
    const float* wr0 = w2 + (2 * og2) * 64;
    const float* wr1 = wr0 + 64;
    for (int c = 0; c < 64; c++) {
      float4 fA = *(const float4*)&h1s[c * 36 + kq2 * 8];
      float4 fB = *(const float4*)&h1s[c * 36 + kq2 * 8 + 4];
      float u = wr0[c], v = wr1[c];
      a2[0] = fmaf(u, fA.x, a2[0]);  a2[1] = fmaf(u, fA.y, a2[1]);
      a2[2] = fmaf(u, fA.z, a2[2]);  a2[3] = fmaf(u, fA.w, a2[3]);
      a2[4] = fmaf(u, fB.x, a2[4]);  a2[5] = fmaf(u, fB.y, a2[5]);
      a2[6] = fmaf(u, fB.z, a2[6]);  a2[7] = fmaf(u, fB.w, a2[7]);
      a2[8] = fmaf(v, fA.x, a2[8]);  a2[9] = fmaf(v, fA.y, a2[9]);
      a2[10] = fmaf(v, fA.z, a2[10]); a2[11] = fmaf(v, fA.w, a2[11]);
      a2[12] = fmaf(v, fB.x, a2[12]); a2[13] = fmaf(v, fB.y, a2[13]);
      a2[14] = fmaf(v, fB.z, a2[14]); a2[15] = fmaf(v, fB.w, a2[15]);
    }
    // relu then max over k == max then relu (relu is monotone)
    float m0 = a2[0], m1 = a2[8];
#pragma unroll
    for (int i = 1; i < 8; i++) { m0 = fmaxf(m0, a2[i]); m1 = fmaxf(m1, a2[8 + i]); }
    m0 = fmaxf(m0, 0.f);
    m1 = fmaxf(m1, 0.f);
    // reduce over the 4 lanes sharing og2 (kq2 = 0..3, adjacent lanes)
    m0 = fmaxf(m0, __shfl_xor(m0, 1, 64));
    m0 = fmaxf(m0, __shfl_xor(m0, 2, 64));
    m1 = fmaxf(m1, __shfl_xor(m1, 1, 64));
    m1 = fmaxf(m1, __shfl_xor(m1, 2, 64));
    if (kq2 == 0) {
      out_np[((size_t)b * 128 + 2 * og2) * NSAMP + s] = m0;
      out_np[((size_t)b * 128 + 2 * og2 + 1) * NSAMP + s] = m1;
    }
  }
}

extern "C" void kernel_launch(void* const* d_in, const int* in_sizes, int n_in,
                              void* d_out, int out_size, void* d_ws, size_t ws_size,
                              hipStream_t stream) {
  (void)in_sizes; (void)n_in; (void)out_size; (void)ws_size;
  const float* xyz = (const float*)d_in[0];
  const float* pts = (const float*)d_in[1];
  const float* att = (const float*)d_in[2];
  const float* w0 = (const float*)d_in[3];
  const float* b0 = (const float*)d_in[4];
  const float* w1 = (const float*)d_in[5];
  const float* b1 = (const float*)d_in[6];
  const float* w2 = (const float*)d_in[7];
  const float* b2 = (const float*)d_in[8];

  float* out = (float*)d_out;
  float* out_newxyz = out;                                           // (B,3,S)
  float* out_newpts = out + NBATCH * 3 * NSAMP;                      // (B,128,S)
  float* out_att = out + NBATCH * 3 * NSAMP + NBATCH * 128 * NSAMP;  // (B,1,S)
  int* idx_ws = (int*)d_ws;  // (B*S, K) int32 = 1 MB

  fps_kernel<<<NBATCH, 256, 0, stream>>>(xyz, out_newxyz);
  ballq_kernel<<<(NBATCH * NSAMP) / 4, 256, 0, stream>>>(xyz, att, out_newxyz, idx_ws, out_att);
  mlp_kernel<<<NBATCH * NSAMP, 256, 0, stream>>>(xyz, pts, out_newxyz, idx_ws,
                                                 w0, b0, w1, b1, w2, b2, out_newpts);
}

// Round 11
// 1338.931 us; speedup vs baseline: 2.2174x; 1.1751x over previous
//
#include <hip/hip_runtime.h>

#define NPTS 8192
#define NSAMP 1024
#define NBATCH 8
#define KNB 32

typedef float f32x2 __attribute__((ext_vector_type(2)));
typedef unsigned long long u64;

// Packed f32 ops — IEEE rn per half, identical results to scalar v_add/v_mul.
__device__ __forceinline__ f32x2 pk_add(f32x2 a, f32x2 b) {
  f32x2 d; asm("v_pk_add_f32 %0, %1, %2" : "=v"(d) : "v"(a), "v"(b)); return d;
}
__device__ __forceinline__ f32x2 pk_mul(f32x2 a, f32x2 b) {
  f32x2 d; asm("v_pk_mul_f32 %0, %1, %2" : "=v"(d) : "v"(a), "v"(b)); return d;
}

// Single-dep-chain DPP reduce rounds (old = own value, safe for min/max).
#define DPP_FMAX_ROUND(v, CTRL)                                                        \
  do {                                                                                 \
    int _b = __float_as_int(v);                                                        \
    int _p = __builtin_amdgcn_update_dpp(_b, _b, CTRL, 0xF, 0xF, false);               \
    (v) = fmaxf((v), __int_as_float(_p));                                              \
  } while (0)

#define DPP_FMIN_ROUND(v, CTRL)                                                        \
  do {                                                                                 \
    int _b = __float_as_int(v);                                                        \
    int _p = __builtin_amdgcn_update_dpp(_b, _b, CTRL, 0xF, 0xF, false);               \
    (v) = fminf((v), __int_as_float(_p));                                              \
  } while (0)

// u64 key min round — used in the post-barrier combine (row_shr/bcast chain).
#define DPP_MIN_ROUND(k, CTRL)                                                         \
  do {                                                                                 \
    unsigned _lo = (unsigned)(k), _hi = (unsigned)((k) >> 32);                         \
    unsigned _plo = (unsigned)__builtin_amdgcn_update_dpp((int)_lo, (int)_lo, CTRL,    \
                                                          0xF, 0xF, false);            \
    unsigned _phi = (unsigned)__builtin_amdgcn_update_dpp((int)_hi, (int)_hi, CTRL,    \
                                                          0xF, 0xF, false);            \
    u64 _ok = (((u64)_phi) << 32) | _plo;                                              \
    if (_ok < (k)) (k) = _ok;                                                          \
  } while (0)

__device__ __forceinline__ u64 umin64(u64 a, u64 b) { return a < b ? a : b; }

// Exact-match squared distance: ((dx*dx + dy*dy) + dz*dz), rn ops, no FMA.
__device__ __forceinline__ float sqdist_rn(float px, float py, float pz,
                                           float qx, float qy, float qz) {
  float dx = px - qx, dy = py - qy, dz = pz - qz;
  return __fadd_rn(__fadd_rn(__fmul_rn(dx, dx), __fmul_rn(dy, dy)), __fmul_rn(dz, dz));
}

// ---------------------------------------------------------------------------
// Kernel 1: farthest point sampling — flat per-lane key publish.
// One block per batch, 512 threads (8 waves), 16 pts/thread, x-sorted
// (bitonic prologue) so each wave owns a contiguous x-slab of 1024 points.
// Per step:
//   skip test: gap^2 >= gmax (GLOBAL max D from last winner key — valid
//   since wave_maxD <= gmax; rn-monotone no-op proof). If active:
//   update (packed math) -> per-lane max bvl -> rescan vs bvl -> per-lane
//   key (~bits(bvl)<<32 | minOrigIdxOfTies). EVERY lane writes its key to
//   LDS (parity-double-buffered, coalesced b64). ONE barrier. Then every
//   wave redundantly combines all 512 keys: 8 pipelined ds_read_b64 +
//   7-min tree + 6 u64 DPP rounds -> readlane(63) -> winner (key carries
//   dist AND index) -> coords via broadcast ds_reads; gmax from hi bits.
// No per-wave pre-barrier reduce chains -> all wave paths equal length ->
// no barrier skew from the skip divergence.
// Exact semantics: min over per-lane keys == argmax by (dist desc, index
// asc) == jnp.argmax first-occurrence; p + (-q) == p - q bitwise; no FMA.
// ---------------------------------------------------------------------------
__global__ __launch_bounds__(512) void fps_kernel(const float* __restrict__ xyz,
                                                  float* __restrict__ out_newxyz) {
  // 96 KB region: first used as u64 sort buffer (64 KB), then as cds[] coords.
  __shared__ __align__(16) char smem_raw[NPTS * 3 * 4];
  u64* sbuf = reinterpret_cast<u64*>(smem_raw);
  float* cds = reinterpret_cast<float*>(smem_raw);  // [n]={x,y,z}, stride 12B
  __shared__ u64 wkeys[2][512];

  const int b = blockIdx.x;
  const int tid = threadIdx.x;
  const int lane = tid & 63;
  const float* xb = xyz + (size_t)b * 3 * NPTS;

  // ---- phase 0: build sort keys (x >= 0 so u32 bit order == float order) ----
  for (int j = 0; j < 16; j++) {
    int n = tid + j * 512;
    float x = xb[n];
    sbuf[n] = (((u64)__float_as_uint(x)) << 32) | (u64)n;
  }
  __syncthreads();

  // ---- bitonic sort ascending, 8192 u64 keys in LDS ----
  for (unsigned k = 2; k <= (unsigned)NPTS; k <<= 1) {
    for (unsigned jm = k >> 1; jm > 0; jm >>= 1) {
      for (int p = 0; p < 16; p++) {
        unsigned i = (unsigned)tid + (unsigned)p * 512u;
        unsigned ixj = i ^ jm;
        if (ixj > i) {
          u64 a = sbuf[i], c = sbuf[ixj];
          bool up = ((i & k) == 0);
          if ((a > c) == up) { sbuf[i] = c; sbuf[ixj] = a; }
        }
      }
      __syncthreads();
    }
  }

  // ---- phase 1: thread t takes sorted slots [t*16, t*16+16) ----
  f32x2 X2[8], Y2[8], Z2[8], D2[8];
  unsigned idxp[8];  // packed original indices: lo16 = .x slot, hi16 = .y slot
  float txmin = 1e30f, txmax = -1e30f;
#pragma unroll
  for (int j = 0; j < 8; j++) {
    u64 k0 = sbuf[tid * 16 + 2 * j];
    u64 k1 = sbuf[tid * 16 + 2 * j + 1];
    unsigned n0 = (unsigned)k0 & 8191u, n1 = (unsigned)k1 & 8191u;
    float x0 = __uint_as_float((unsigned)(k0 >> 32));
    float x1 = __uint_as_float((unsigned)(k1 >> 32));
    X2[j].x = x0; X2[j].y = x1;
    Y2[j].x = xb[NPTS + n0];     Y2[j].y = xb[NPTS + n1];
    Z2[j].x = xb[2 * NPTS + n0]; Z2[j].y = xb[2 * NPTS + n1];
    D2[j].x = 1e10f;             D2[j].y = 1e10f;
    idxp[j] = n0 | (n1 << 16);
    txmin = fminf(txmin, fminf(x0, x1));
    txmax = fmaxf(txmax, fmaxf(x0, x1));
  }
  // wave x-bounds from actual loaded values (sort bugs could only hurt speed)
  DPP_FMIN_ROUND(txmin, 0x111); DPP_FMIN_ROUND(txmin, 0x112);
  DPP_FMIN_ROUND(txmin, 0x114); DPP_FMIN_ROUND(txmin, 0x118);
  DPP_FMIN_ROUND(txmin, 0x142); DPP_FMIN_ROUND(txmin, 0x143);
  DPP_FMAX_ROUND(txmax, 0x111); DPP_FMAX_ROUND(txmax, 0x112);
  DPP_FMAX_ROUND(txmax, 0x114); DPP_FMAX_ROUND(txmax, 0x118);
  DPP_FMAX_ROUND(txmax, 0x142); DPP_FMAX_ROUND(txmax, 0x143);
  const float xlo = __int_as_float(__builtin_amdgcn_readlane(__float_as_int(txmin), 63));
  const float xhi = __int_as_float(__builtin_amdgcn_readlane(__float_as_int(txmax), 63));
  __syncthreads();  // done reading sbuf

  // ---- phase 2: overlay cds (coords by ORIGINAL index) ----
#pragma unroll
  for (int j = 0; j < 8; j++) {
    unsigned n0 = idxp[j] & 0xFFFFu, n1 = idxp[j] >> 16;
    cds[n0 * 3 + 0] = X2[j].x; cds[n0 * 3 + 1] = Y2[j].x; cds[n0 * 3 + 2] = Z2[j].x;
    cds[n1 * 3 + 0] = X2[j].y; cds[n1 * 3 + 1] = Y2[j].y; cds[n1 * 3 + 2] = Z2[j].y;
  }
  __syncthreads();

  // selection 0 = point 0
  float sx = cds[0], sy = cds[1], sz = cds[2];
  unsigned c0i = 0, c1i = 0;   // per-thread stash of selection indices
  float gmax = 1e30f;          // global max D (wave-uniform; no skip at t=0)
  u64 key_cache = ~0ull;       // this lane's cached key

  for (int t = 0; t < NSAMP; t++) {
    // ---- wave-uniform skip test vs GLOBAL max D (rn-monotone lower bound) ----
    float gap = fmaxf(fmaxf(xlo - sx, sx - xhi), 0.0f);
    float lb = __fmul_rn(gap, gap);
    const int par = t & 1;

    if (lb < gmax) {
      // ---- distance update (packed math) ----
      f32x2 nqx, nqy, nqz;
      nqx.x = -sx; nqx.y = -sx;
      nqy.x = -sy; nqy.y = -sy;
      nqz.x = -sz; nqz.y = -sz;
      float bvx = -1.0f, bvy = -1.0f;
#pragma unroll
      for (int j = 0; j < 8; j++) {
        f32x2 dx = pk_add(X2[j], nqx);
        f32x2 dy = pk_add(Y2[j], nqy);
        f32x2 dz = pk_add(Z2[j], nqz);
        f32x2 dd = pk_add(pk_add(pk_mul(dx, dx), pk_mul(dy, dy)), pk_mul(dz, dz));
        float m0 = fminf(D2[j].x, dd.x);
        float m1 = fminf(D2[j].y, dd.y);
        D2[j].x = m0;
        D2[j].y = m1;
        bvx = fmaxf(bvx, m0);
        bvy = fmaxf(bvy, m1);
      }
      const float bvl = fmaxf(bvx, bvy);  // this lane's max D

      // ---- rescan vs bvl: min ORIGINAL index among this lane's ties ----
      unsigned cand = 0xFFFFFFFFu;
#pragma unroll
      for (int j = 0; j < 8; j++) {
        unsigned n0 = idxp[j] & 0xFFFFu, n1 = idxp[j] >> 16;
        if (D2[j].y == bvl && n1 < cand) cand = n1;
        if (D2[j].x == bvl && n0 < cand) cand = n0;
      }

      key_cache = (((u64)(~__float_as_uint(bvl))) << 32) | (u64)cand;
    }
    // every lane publishes its (possibly cached) key — equal path lengths
    wkeys[par][tid] = key_cache;
    __syncthreads();

    // ---- combine all 512 lane keys (redundantly in every wave) ----
    u64 k0 = wkeys[par][lane];
    u64 k1 = wkeys[par][64 + lane];
    u64 k2 = wkeys[par][128 + lane];
    u64 k3 = wkeys[par][192 + lane];
    u64 k4 = wkeys[par][256 + lane];
    u64 k5 = wkeys[par][320 + lane];
    u64 k6 = wkeys[par][384 + lane];
    u64 k7 = wkeys[par][448 + lane];
    u64 ka = umin64(umin64(k0, k1), umin64(k2, k3));
    u64 kb = umin64(umin64(k4, k5), umin64(k6, k7));
    u64 k = umin64(ka, kb);
    DPP_MIN_ROUND(k, 0x111);  // row_shr 1
    DPP_MIN_ROUND(k, 0x112);  // row_shr 2
    DPP_MIN_ROUND(k, 0x114);  // row_shr 4
    DPP_MIN_ROUND(k, 0x118);  // row_shr 8
    DPP_MIN_ROUND(k, 0x142);  // bcast15
    DPP_MIN_ROUND(k, 0x143);  // bcast31  -> full min in lane 63
    unsigned wlo = (unsigned)__builtin_amdgcn_readlane((int)(unsigned)k, 63);
    unsigned whi = (unsigned)__builtin_amdgcn_readlane((int)(unsigned)(k >> 32), 63);
    unsigned wid = wlo & 8191u;
    gmax = __uint_as_float(~whi);  // winner distance = new global max D

    // stash: selection (t+1) = wid  (selection 0 preset above)
    if (t + 1 == tid) c0i = wid;
    if (t + 1 == tid + 512) c1i = wid;

    // winner coords from LDS (uniform addr -> broadcast)
    sx = cds[wid * 3 + 0];
    sy = cds[wid * 3 + 1];
    sz = cds[wid * 3 + 2];
  }

  // epilogue: thread tid writes new_xyz columns tid and tid+512
  {
    float ax = cds[c0i * 3 + 0], ay = cds[c0i * 3 + 1], az = cds[c0i * 3 + 2];
    float bx = cds[c1i * 3 + 0], by = cds[c1i * 3 + 1], bz = cds[c1i * 3 + 2];
    out_newxyz[(b * 3 + 0) * NSAMP + tid] = ax;
    out_newxyz[(b * 3 + 1) * NSAMP + tid] = ay;
    out_newxyz[(b * 3 + 2) * NSAMP + tid] = az;
    out_newxyz[(b * 3 + 0) * NSAMP + 512 + tid] = bx;
    out_newxyz[(b * 3 + 1) * NSAMP + 512 + tid] = by;
    out_newxyz[(b * 3 + 2) * NSAMP + 512 + tid] = bz;
  }
}

// ---------------------------------------------------------------------------
// Kernel 2: ball query + attention mean. One wave per (b,s). Scans points in
// ascending index order in chunks of 64, collects the first K in-radius
// indices (ballot + prefix popcount), pads with the first hit.
// ---------------------------------------------------------------------------
__global__ __launch_bounds__(256) void ballq_kernel(const float* __restrict__ xyz,
                                                    const float* __restrict__ att,
                                                    const float* __restrict__ newxyz,
                                                    int* __restrict__ idx_out,
                                                    float* __restrict__ att_out) {
  __shared__ int rowbuf[4][KNB];
  const int wv = threadIdx.x >> 6;
  const int lane = threadIdx.x & 63;
  const int g = blockIdx.x * 4 + wv;  // b*NSAMP + s
  const int b = g >> 10;
  const int s = g & 1023;
  const float* xb = xyz + (size_t)b * 3 * NPTS;

  float qx = newxyz[(b * 3 + 0) * NSAMP + s];
  float qy = newxyz[(b * 3 + 1) * NSAMP + s];
  float qz = newxyz[(b * 3 + 2) * NSAMP + s];

  int have = 0;
  int firstn = 0;
  for (int c = 0; c < NPTS / 64; c++) {
    int n = c * 64 + lane;
    float dd = sqdist_rn(xb[n], xb[NPTS + n], xb[2 * NPTS + n], qx, qy, qz);
    bool inb = (dd <= 0.04f);
    unsigned long long m = __ballot(inb);
    if (have == 0 && m != 0ull) firstn = c * 64 + __builtin_ctzll(m);
    int pre = __popcll(m & ((1ull << lane) - 1ull));
    if (inb && (have + pre) < KNB) rowbuf[wv][have + pre] = n;
    have += __popcll(m);
    if (have >= KNB) break;
  }
  if (have > KNB) have = KNB;
  if (lane < KNB && lane >= have) rowbuf[wv][lane] = firstn;  // pad

  float av = 0.0f;
  if (lane < KNB) {
    int myidx = rowbuf[wv][lane];
    idx_out[(size_t)g * KNB + lane] = myidx;
    av = att[(size_t)b * NPTS + myidx];
  }
#pragma unroll
  for (int m = 1; m < 64; m <<= 1) av += __shfl_xor(av, m, 64);
  if (lane == 0) att_out[g] = av * 0.03125f;  // mean over K=32 (exact /32)
}

// ---------------------------------------------------------------------------
// Kernel 3: gather features + 3-layer MLP + max over K. One 256-thread block
// per (b,s). feat [67][32] and h [64][36] (padded stride) in LDS; weights
// streamed from global (L1/L2 broadcast). f32 fmaf throughout.
// ---------------------------------------------------------------------------
__global__ __launch_bounds__(256) void mlp_kernel(
    const float* __restrict__ xyz, const float* __restrict__ pts,
    const float* __restrict__ newxyz, const int* __restrict__ idx,
    const float* __restrict__ w0, const float* __restrict__ b0,
    const float* __restrict__ w1, const float* __restrict__ b1,
    const float* __restrict__ w2, const float* __restrict__ b2,
    float* __restrict__ out_np) {
  const int g = blockIdx.x;
  const int b = g >> 10;
  const int s = g & 1023;
  const int t = threadIdx.x;

  __shared__ __align__(16) float feat[67 * 32];
  __shared__ __align__(16) float h0s[64 * 36];
  __shared__ __align__(16) float h1s[64 * 36];
  __shared__ int sidx[KNB];

  if (t < KNB) sidx[t] = idx[(size_t)g * KNB + t];
  __syncthreads();

  // gather: rows 0..2 = g_norm (xyz - query), rows 3..66 = point features
  {
    int k = t & 31, rg = t >> 5;
    int n = sidx[k];
    const float* pb = pts + (size_t)b * 64 * NPTS;
    for (int r = rg; r < 67; r += 8) {
      float v;
      if (r < 3)
        v = xyz[((size_t)b * 3 + r) * NPTS + n] - newxyz[(b * 3 + r) * NSAMP + s];
      else
        v = pb[(size_t)(r - 3) * NPTS + n];
      feat[r * 32 + k] = v;
    }
  }
  __syncthreads();

  const int kq = t & 7;   // k block = 4*kq .. +4
  const int og = t >> 3;  // o = 2*og, 2*og+1

  // ---- layer 0: 67 -> 64 ----
  {
    float a0[8];
    float bu = b0[2 * og], bw = b0[2 * og + 1];
    a0[0] = a0[1] = a0[2] = a0[3] = bu;
    a0[4] = a0[5] = a0[6] = a0[7] = bw;
    const float* wr0 = w0 + (2 * og) * 67;
    const float* wr1 = wr0 + 67;
    for (int c = 0; c < 67; c++) {
      float4 f = *(const float4*)&feat[c * 32 + kq * 4];
      float u = wr0[c], v = wr1[c];
      a0[0] = fmaf(u, f.x, a0[0]); a0[1] = fmaf(u, f.y, a0[1]);
      a0[2] = fmaf(u, f.z, a0[2]); a0[3] = fmaf(u, f.w, a0[3]);
      a0[4] = fmaf(v, f.x, a0[4]); a0[5] = fmaf(v, f.y, a0[5]);
      a0[6] = fmaf(v, f.z, a0[6]); a0[7] = fmaf(v, f.w, a0[7]);
    }
    float4 r0, r1;
    r0.x = fmaxf(a0[0], 0.f); r0.y = fmaxf(a0[1], 0.f);
    r0.z = fmaxf(a0[2], 0.f); r0.w = fmaxf(a0[3], 0.f);
    r1.x = fmaxf(a0[4], 0.f); r1.y = fmaxf(a0[5], 0.f);
    r1.z = fmaxf(a0[6], 0.f); r1.w = fmaxf(a0[7], 0.f);
    *(float4*)&h0s[(2 * og) * 36 + kq * 4] = r0;
    *(float4*)&h0s[(2 * og + 1) * 36 + kq * 4] = r1;
  }
  __syncthreads();

  // ---- layer 1: 64 -> 64 ----
  {
    float a1[8];
    float bu = b1[2 * og], bw = b1[2 * og + 1];
    a1[0] = a1[1] = a1[2] = a1[3] = bu;
    a1[4] = a1[5] = a1[6] = a1[7] = bw;
    const float* wr0 = w1 + (2 * og) * 64;
    const float* wr1 = wr0 + 64;
    for (int c = 0; c < 64; c++) {
      float4 f = *(const float4*)&h0s[c * 36 + kq * 4];
      float u = wr0[c], v = wr1[c];
      a1[0] = fmaf(u, f.x, a1[0]); a1[1] = fmaf(u, f.y, a1[1]);
      a1[2] = fmaf(u, f.z, a1[2]); a1[3] = fmaf(u, f.w, a1[3]);
      a1[4] = fmaf(v, f.x, a1[4]); a1[5] = fmaf(v, f.y, a1[5]);
      a1[6] = fmaf(v, f.z, a1[6]); a1[7] = fmaf(v, f.w, a1[7]);
    }
    float4 r0, r1;
    r0.x = fmaxf(a1[0], 0.f); r0.y = fmaxf(a1[1], 0.f);
    r0.z = fmaxf(a1[2], 0.f); r0.w = fmaxf(a1[3], 0.f);
    r1.x = fmaxf(a1[4], 0.f); r1.y = fmaxf(a1[5], 0.f);
    r1.z = fmaxf(a1[6], 0.f); r1.w = fmaxf(a1[7], 0.f);
    *(float4*)&h1s[(2 * og) * 36 + kq * 4] = r0;
    *(float4*)&h1s[(2 * og + 1) * 36 + kq * 4] = r1;
  }
  __syncthreads();

  // ---- layer 2: 64 -> 128, then max over k ----
  {
    const int kq2 = t & 3;   // k block = 8*kq2 .. +8
    const int og2 = t >> 2;  // o = 2*og2, 2*og2+1
    float a2[16];
    float bu = b2[2 * og2], bw = b2[2 * og2 + 1];
#pragma unroll
    for (int i = 0; i < 8; i++) { a2[i] = bu; a2[8 + i] = bw; }
    const float* wr0 = w2 + (2 * og2) * 64;
    const float* wr1 = wr0 + 64;
    for (int c = 0; c < 64; c++) {
      float4 fA = *(const float4*)&h1s[c * 36 + kq2 * 8];
      float4 fB = *(const float4*)&h1s[c * 36 + kq2 * 8 + 4];
      float u = wr0[c], v = wr1[c];
      a2[0] = fmaf(u, fA.x, a2[0]);  a2[1] = fmaf(u, fA.y, a2[1]);
      a2[2] = fmaf(u, fA.z, a2[2]);  a2[3] = fmaf(u, fA.w, a2[3]);
      a2[4] = fmaf(u, fB.x, a2[4]);  a2[5] = fmaf(u, fB.y, a2[5]);
      a2[6] = fmaf(u, fB.z, a2[6]);  a2[7] = fmaf(u, fB.w, a2[7]);
      a2[8] = fmaf(v, fA.x, a2[8]);  a2[9] = fmaf(v, fA.y, a2[9]);
      a2[10] = fmaf(v, fA.z, a2[10]); a2[11] = fmaf(v, fA.w, a2[11]);
      a2[12] = fmaf(v, fB.x, a2[12]); a2[13] = fmaf(v, fB.y, a2[13]);
      a2[14] = fmaf(v, fB.z, a2[14]); a2[15] = fmaf(v, fB.w, a2[15]);
    }
    // relu then max over k == max then relu (relu is monotone)
    float m0 = a2[0], m1 = a2[8];
#pragma unroll
    for (int i = 1; i < 8; i++) { m0 = fmaxf(m0, a2[i]); m1 = fmaxf(m1, a2[8 + i]); }
    m0 = fmaxf(m0, 0.f);
    m1 = fmaxf(m1, 0.f);
    // reduce over the 4 lanes sharing og2 (kq2 = 0..3, adjacent lanes)
    m0 = fmaxf(m0, __shfl_xor(m0, 1, 64));
    m0 = fmaxf(m0, __shfl_xor(m0, 2, 64));
    m1 = fmaxf(m1, __shfl_xor(m1, 1, 64));
    m1 = fmaxf(m1, __shfl_xor(m1, 2, 64));
    if (kq2 == 0) {
      out_np[((size_t)b * 128 + 2 * og2) * NSAMP + s] = m0;
      out_np[((size_t)b * 128 + 2 * og2 + 1) * NSAMP + s] = m1;
    }
  }
}

extern "C" void kernel_launch(void* const* d_in, const int* in_sizes, int n_in,
                              void* d_out, int out_size, void* d_ws, size_t ws_size,
                              hipStream_t stream) {
  (void)in_sizes; (void)n_in; (void)out_size; (void)ws_size;
  const float* xyz = (const float*)d_in[0];
  const float* pts = (const float*)d_in[1];
  const float* att = (const float*)d_in[2];
  const float* w0 = (const float*)d_in[3];
  const float* b0 = (const float*)d_in[4];
  const float* w1 = (const float*)d_in[5];
  const float* b1 = (const float*)d_in[6];
  const float* w2 = (const float*)d_in[7];
  const float* b2 = (const float*)d_in[8];

  float* out = (float*)d_out;
  float* out_newxyz = out;                                           // (B,3,S)
  float* out_newpts = out + NBATCH * 3 * NSAMP;                      // (B,128,S)
  float* out_att = out + NBATCH * 3 * NSAMP + NBATCH * 128 * NSAMP;  // (B,1,S)
  int* idx_ws = (int*)d_ws;  // (B*S, K) int32 = 1 MB

  fps_kernel<<<NBATCH, 512, 0, stream>>>(xyz, out_newxyz);
  ballq_kernel<<<(NBATCH * NSAMP) / 4, 256, 0, stream>>>(xyz, att, out_newxyz, idx_ws, out_att);
  mlp_kernel<<<NBATCH * NSAMP, 256, 0, stream>>>(xyz, pts, out_newxyz, idx_ws,
                                                 w0, b0, w1, b1, w2, b2, out_newpts);
}

// Round 12
// 1133.442 us; speedup vs baseline: 2.6194x; 1.1813x over previous
//
#include <hip/hip_runtime.h>

#define NPTS 8192
#define NSAMP 1024
#define NBATCH 8
#define KNB 32

typedef float f32x2 __attribute__((ext_vector_type(2)));
typedef unsigned long long u64;

// Packed f32 ops — IEEE rn per half, identical results to scalar v_add/v_mul.
__device__ __forceinline__ f32x2 pk_add(f32x2 a, f32x2 b) {
  f32x2 d; asm("v_pk_add_f32 %0, %1, %2" : "=v"(d) : "v"(a), "v"(b)); return d;
}
__device__ __forceinline__ f32x2 pk_mul(f32x2 a, f32x2 b) {
  f32x2 d; asm("v_pk_mul_f32 %0, %1, %2" : "=v"(d) : "v"(a), "v"(b)); return d;
}

// Single-dep-chain DPP reduce rounds (old = own value, safe for min/max).
#define DPP_FMAX_ROUND(v, CTRL)                                                        \
  do {                                                                                 \
    int _b = __float_as_int(v);                                                        \
    int _p = __builtin_amdgcn_update_dpp(_b, _b, CTRL, 0xF, 0xF, false);               \
    (v) = fmaxf((v), __int_as_float(_p));                                              \
  } while (0)

#define DPP_FMIN_ROUND(v, CTRL)                                                        \
  do {                                                                                 \
    int _b = __float_as_int(v);                                                        \
    int _p = __builtin_amdgcn_update_dpp(_b, _b, CTRL, 0xF, 0xF, false);               \
    (v) = fminf((v), __int_as_float(_p));                                              \
  } while (0)

#define DPP_UMIN_ROUND(v, CTRL)                                                        \
  do {                                                                                 \
    unsigned _p = (unsigned)__builtin_amdgcn_update_dpp((int)(v), (int)(v), CTRL,      \
                                                        0xF, 0xF, false);              \
    if (_p < (v)) (v) = _p;                                                            \
  } while (0)

// u64 key min round — used for the 3 cross-wave rounds.
#define DPP_MIN_ROUND(k, CTRL)                                                         \
  do {                                                                                 \
    unsigned _lo = (unsigned)(k), _hi = (unsigned)((k) >> 32);                         \
    unsigned _plo = (unsigned)__builtin_amdgcn_update_dpp((int)_lo, (int)_lo, CTRL,    \
                                                          0xF, 0xF, false);            \
    unsigned _phi = (unsigned)__builtin_amdgcn_update_dpp((int)_hi, (int)_hi, CTRL,    \
                                                          0xF, 0xF, false);            \
    u64 _ok = (((u64)_phi) << 32) | _plo;                                              \
    if (_ok < (k)) (k) = _ok;                                                          \
  } while (0)

// Exact-match squared distance: ((dx*dx + dy*dy) + dz*dz), rn ops, no FMA.
__device__ __forceinline__ float sqdist_rn(float px, float py, float pz,
                                           float qx, float qy, float qz) {
  float dx = px - qx, dy = py - qy, dz = pz - qz;
  return __fadd_rn(__fadd_rn(__fmul_rn(dx, dx), __fmul_rn(dy, dy)), __fmul_rn(dz, dz));
}

// ---------------------------------------------------------------------------
// Kernel 1: farthest point sampling (R7 structure — best measured: 953 us).
// One block per batch, 512 threads (8 waves), 16 points/thread, x-sorted
// (bitonic prologue) so each wave owns a contiguous x-slab of 1024 points.
// Per step (active wave): skip test (gap^2 >= wave max D, rn-monotone) ->
// else full path: packed-math update -> 6-DPP value max -> readlane ->
// descending rescan (min ORIG index tie-break) -> 6-DPP index min ->
// u64 key. lane63 publishes; ONE barrier; 3 u64 DPP rounds across 8 wave
// slots; readfirstlane; coords via broadcast ds_reads.
// Exact semantics: min over keys == argmax by (dist desc, index asc) ==
// jnp.argmax first-occurrence; p + (-q) == p - q bitwise; no FMA contraction.
// ---------------------------------------------------------------------------
__global__ __launch_bounds__(512) void fps_kernel(const float* __restrict__ xyz,
                                                  float* __restrict__ out_newxyz) {
  // 96 KB region: first used as u64 sort buffer (64 KB), then as cds[] coords.
  __shared__ __align__(16) char smem_raw[NPTS * 3 * 4];
  u64* sbuf = reinterpret_cast<u64*>(smem_raw);
  float* cds = reinterpret_cast<float*>(smem_raw);  // [n]={x,y,z}, stride 12B
  __shared__ u64 wkeys[2][8];

  const int b = blockIdx.x;
  const int tid = threadIdx.x;
  const int lane = tid & 63;
  const int wv = tid >> 6;
  const float* xb = xyz + (size_t)b * 3 * NPTS;

  // ---- phase 0: build sort keys (x >= 0 so u32 bit order == float order) ----
  for (int j = 0; j < 16; j++) {
    int n = tid + j * 512;
    float x = xb[n];
    sbuf[n] = (((u64)__float_as_uint(x)) << 32) | (u64)n;
  }
  __syncthreads();

  // ---- bitonic sort ascending, 8192 u64 keys in LDS ----
  for (unsigned k = 2; k <= (unsigned)NPTS; k <<= 1) {
    for (unsigned jm = k >> 1; jm > 0; jm >>= 1) {
      for (int p = 0; p < 16; p++) {
        unsigned i = (unsigned)tid + (unsigned)p * 512u;
        unsigned ixj = i ^ jm;
        if (ixj > i) {
          u64 a = sbuf[i], c = sbuf[ixj];
          bool up = ((i & k) == 0);
          if ((a > c) == up) { sbuf[i] = c; sbuf[ixj] = a; }
        }
      }
      __syncthreads();
    }
  }

  // ---- phase 1: thread t takes sorted slots [t*16, t*16+16) ----
  f32x2 X2[8], Y2[8], Z2[8], D2[8];
  unsigned idxp[8];  // packed original indices: lo16 = .x slot, hi16 = .y slot
  float txmin = 1e30f, txmax = -1e30f;
#pragma unroll
  for (int j = 0; j < 8; j++) {
    u64 k0 = sbuf[tid * 16 + 2 * j];
    u64 k1 = sbuf[tid * 16 + 2 * j + 1];
    unsigned n0 = (unsigned)k0 & 8191u, n1 = (unsigned)k1 & 8191u;
    float x0 = __uint_as_float((unsigned)(k0 >> 32));
    float x1 = __uint_as_float((unsigned)(k1 >> 32));
    X2[j].x = x0; X2[j].y = x1;
    Y2[j].x = xb[NPTS + n0];     Y2[j].y = xb[NPTS + n1];
    Z2[j].x = xb[2 * NPTS + n0]; Z2[j].y = xb[2 * NPTS + n1];
    D2[j].x = 1e10f;             D2[j].y = 1e10f;
    idxp[j] = n0 | (n1 << 16);
    txmin = fminf(txmin, fminf(x0, x1));
    txmax = fmaxf(txmax, fmaxf(x0, x1));
  }
  // wave x-bounds from actual values (sort bugs could only hurt speed)
  DPP_FMIN_ROUND(txmin, 0x111); DPP_FMIN_ROUND(txmin, 0x112);
  DPP_FMIN_ROUND(txmin, 0x114); DPP_FMIN_ROUND(txmin, 0x118);
  DPP_FMIN_ROUND(txmin, 0x142); DPP_FMIN_ROUND(txmin, 0x143);
  DPP_FMAX_ROUND(txmax, 0x111); DPP_FMAX_ROUND(txmax, 0x112);
  DPP_FMAX_ROUND(txmax, 0x114); DPP_FMAX_ROUND(txmax, 0x118);
  DPP_FMAX_ROUND(txmax, 0x142); DPP_FMAX_ROUND(txmax, 0x143);
  const float xlo = __int_as_float(__builtin_amdgcn_readlane(__float_as_int(txmin), 63));
  const float xhi = __int_as_float(__builtin_amdgcn_readlane(__float_as_int(txmax), 63));
  __syncthreads();  // done reading sbuf

  // ---- phase 2: overlay cds (coords by ORIGINAL index) ----
#pragma unroll
  for (int j = 0; j < 8; j++) {
    unsigned n0 = idxp[j] & 0xFFFFu, n1 = idxp[j] >> 16;
    cds[n0 * 3 + 0] = X2[j].x; cds[n0 * 3 + 1] = Y2[j].x; cds[n0 * 3 + 2] = Z2[j].x;
    cds[n1 * 3 + 0] = X2[j].y; cds[n1 * 3 + 1] = Y2[j].y; cds[n1 * 3 + 2] = Z2[j].y;
  }
  __syncthreads();

  // selection 0 = point 0
  float sx = cds[0], sy = cds[1], sz = cds[2];
  unsigned c0i = 0, c1i = 0;   // per-thread stash of selection indices
  float bv_cache = 1e10f;      // wave max D (wave-uniform)
  u64 key_cache = ~0ull;       // wave's published key

  for (int t = 0; t < NSAMP; t++) {
    // ---- wave-uniform skip test (rn-monotone lower bound) ----
    float gap = fmaxf(fmaxf(xlo - sx, sx - xhi), 0.0f);
    float lb = __fmul_rn(gap, gap);

    if (lb < bv_cache) {
      // ---- full path: distance update (packed math) ----
      f32x2 nqx, nqy, nqz;
      nqx.x = -sx; nqx.y = -sx;
      nqy.x = -sy; nqy.y = -sy;
      nqz.x = -sz; nqz.y = -sz;
      float bvx = -1.0f, bvy = -1.0f;
#pragma unroll
      for (int j = 0; j < 8; j++) {
        f32x2 dx = pk_add(X2[j], nqx);
        f32x2 dy = pk_add(Y2[j], nqy);
        f32x2 dz = pk_add(Z2[j], nqz);
        f32x2 dd = pk_add(pk_add(pk_mul(dx, dx), pk_mul(dy, dy)), pk_mul(dz, dz));
        float m0 = fminf(D2[j].x, dd.x);
        float m1 = fminf(D2[j].y, dd.y);
        D2[j].x = m0;
        D2[j].y = m1;
        bvx = fmaxf(bvx, m0);
        bvy = fmaxf(bvy, m1);
      }
      float bv = fmaxf(bvx, bvy);

      DPP_FMAX_ROUND(bv, 0x111);
      DPP_FMAX_ROUND(bv, 0x112);
      DPP_FMAX_ROUND(bv, 0x114);
      DPP_FMAX_ROUND(bv, 0x118);
      DPP_FMAX_ROUND(bv, 0x142);
      DPP_FMAX_ROUND(bv, 0x143);
      float wval = __int_as_float(__builtin_amdgcn_readlane(__float_as_int(bv), 63));

      // rescan for == wval, tracking min ORIGINAL index
      unsigned cand = 0xFFFFFFFFu;
#pragma unroll
      for (int j = 0; j < 8; j++) {
        unsigned n0 = idxp[j] & 0xFFFFu, n1 = idxp[j] >> 16;
        if (D2[j].y == wval && n1 < cand) cand = n1;
        if (D2[j].x == wval && n0 < cand) cand = n0;
      }
      DPP_UMIN_ROUND(cand, 0x111);
      DPP_UMIN_ROUND(cand, 0x112);
      DPP_UMIN_ROUND(cand, 0x114);
      DPP_UMIN_ROUND(cand, 0x118);
      DPP_UMIN_ROUND(cand, 0x142);
      DPP_UMIN_ROUND(cand, 0x143);

      key_cache = (((u64)(~__float_as_uint(wval))) << 32) | (u64)cand;
      bv_cache = wval;
    }
    // (skip path: key_cache/bv_cache unchanged — provably identical state)

    const int par = t & 1;
    if (lane == 63) wkeys[par][wv] = key_cache;
    __syncthreads();
    u64 k8 = wkeys[par][lane & 7];
    DPP_MIN_ROUND(k8, 0xB1);   // quad_perm ^1
    DPP_MIN_ROUND(k8, 0x4E);   // quad_perm ^2
    DPP_MIN_ROUND(k8, 0x141);  // row_half_mirror
    unsigned wid = (unsigned)__builtin_amdgcn_readfirstlane((int)(unsigned)k8);

    // stash: selection (t+1) = wid  (selection 0 preset above)
    if (t + 1 == tid) c0i = wid;
    if (t + 1 == tid + 512) c1i = wid;

    // winner coords from LDS (uniform addr -> broadcast)
    sx = cds[wid * 3 + 0];
    sy = cds[wid * 3 + 1];
    sz = cds[wid * 3 + 2];
  }

  // epilogue: thread tid writes new_xyz columns tid and tid+512
  {
    float ax = cds[c0i * 3 + 0], ay = cds[c0i * 3 + 1], az = cds[c0i * 3 + 2];
    float bx = cds[c1i * 3 + 0], by = cds[c1i * 3 + 1], bz = cds[c1i * 3 + 2];
    out_newxyz[(b * 3 + 0) * NSAMP + tid] = ax;
    out_newxyz[(b * 3 + 1) * NSAMP + tid] = ay;
    out_newxyz[(b * 3 + 2) * NSAMP + tid] = az;
    out_newxyz[(b * 3 + 0) * NSAMP + 512 + tid] = bx;
    out_newxyz[(b * 3 + 1) * NSAMP + 512 + tid] = by;
    out_newxyz[(b * 3 + 2) * NSAMP + 512 + tid] = bz;
  }
}

// ---------------------------------------------------------------------------
// Kernel 2 (fused consumer): per sample — ball query (wave 0, indices to
// LDS) + attention mean + gather + 3-layer MLP + max-pool. One 256-thread
// block per (b,s); ~27 KB LDS keeps ~5 blocks/CU so gather locality and
// latency hiding match the previous split mlp_kernel. w1/w2 weight rows are
// 256 B-strided -> aligned float4 loads (FMA order unchanged, bitwise-same).
// ---------------------------------------------------------------------------
__global__ __launch_bounds__(256) void sample_kernel(
    const float* __restrict__ xyz, const float* __restrict__ pts,
    const float* __restrict__ att, const float* __restrict__ newxyz,
    const float* __restrict__ w0, const float* __restrict__ b0,
    const float* __restrict__ w1, const float* __restrict__ b1,
    const float* __restrict__ w2, const float* __restrict__ b2,
    float* __restrict__ out_np, float* __restrict__ att_out) {
  const int g = blockIdx.x;
  const int b = g >> 10;
  const int s = g & 1023;
  const int t = threadIdx.x;

  __shared__ __align__(16) float feat[67 * 32];
  __shared__ __align__(16) float h0s[64 * 36];
  __shared__ __align__(16) float h1s[64 * 36];
  __shared__ int sidx[KNB];
  __shared__ float qs[3];

  const float* xb = xyz + (size_t)b * 3 * NPTS;

  // ---- wave 0: ball query (first-K in index order) + attention mean ----
  if (t < 64) {
    const int lane = t;
    float qx = newxyz[(b * 3 + 0) * NSAMP + s];
    float qy = newxyz[(b * 3 + 1) * NSAMP + s];
    float qz = newxyz[(b * 3 + 2) * NSAMP + s];
    if (lane == 0) { qs[0] = qx; qs[1] = qy; qs[2] = qz; }

    int have = 0;
    int firstn = 0;
    for (int c = 0; c < NPTS / 64; c++) {
      int n = c * 64 + lane;
      float dd = sqdist_rn(xb[n], xb[NPTS + n], xb[2 * NPTS + n], qx, qy, qz);
      bool inb = (dd <= 0.04f);
      unsigned long long m = __ballot(inb);
      if (have == 0 && m != 0ull) firstn = c * 64 + __builtin_ctzll(m);
      int pre = __popcll(m & ((1ull << lane) - 1ull));
      if (inb && (have + pre) < KNB) sidx[have + pre] = n;
      have += __popcll(m);
      if (have >= KNB) break;
    }
    if (have > KNB) have = KNB;
    if (lane < KNB && lane >= have) sidx[lane] = firstn;  // pad with first hit

    float av = 0.0f;
    if (lane < KNB) av = att[(size_t)b * NPTS + sidx[lane]];
#pragma unroll
    for (int m = 1; m < 64; m <<= 1) av += __shfl_xor(av, m, 64);
    if (lane == 0) att_out[g] = av * 0.03125f;  // mean over K=32 (exact /32)
  }
  __syncthreads();

  // ---- gather: rows 0..2 = g_norm (xyz - query), rows 3..66 = features ----
  {
    int k = t & 31, rg = t >> 5;
    int n = sidx[k];
    const float* pb = pts + (size_t)b * 64 * NPTS;
    for (int r = rg; r < 67; r += 8) {
      float v;
      if (r < 3)
        v = xyz[((size_t)b * 3 + r) * NPTS + n] - qs[r];
      else
        v = pb[(size_t)(r - 3) * NPTS + n];
      feat[r * 32 + k] = v;
    }
  }
  __syncthreads();

  const int kq = t & 7;   // k block = 4*kq .. +4
  const int og = t >> 3;  // o = 2*og, 2*og+1

  // ---- layer 0: 67 -> 64 (w0 rows are 268B-strided: scalar loads) ----
  {
    float a0[8];
    float bu = b0[2 * og], bw = b0[2 * og + 1];
    a0[0] = a0[1] = a0[2] = a0[3] = bu;
    a0[4] = a0[5] = a0[6] = a0[7] = bw;
    const float* wr0 = w0 + (2 * og) * 67;
    const float* wr1 = wr0 + 67;
    for (int c = 0; c < 67; c++) {
      float4 f = *(const float4*)&feat[c * 32 + kq * 4];
      float u = wr0[c], v = wr1[c];
      a0[0] = fmaf(u, f.x, a0[0]); a0[1] = fmaf(u, f.y, a0[1]);
      a0[2] = fmaf(u, f.z, a0[2]); a0[3] = fmaf(u, f.w, a0[3]);
      a0[4] = fmaf(v, f.x, a0[4]); a0[5] = fmaf(v, f.y, a0[5]);
      a0[6] = fmaf(v, f.z, a0[6]); a0[7] = fmaf(v, f.w, a0[7]);
    }
    float4 r0, r1;
    r0.x = fmaxf(a0[0], 0.f); r0.y = fmaxf(a0[1], 0.f);
    r0.z = fmaxf(a0[2], 0.f); r0.w = fmaxf(a0[3], 0.f);
    r1.x = fmaxf(a0[4], 0.f); r1.y = fmaxf(a0[5], 0.f);
    r1.z = fmaxf(a0[6], 0.f); r1.w = fmaxf(a0[7], 0.f);
    *(float4*)&h0s[(2 * og) * 36 + kq * 4] = r0;
    *(float4*)&h0s[(2 * og + 1) * 36 + kq * 4] = r1;
  }
  __syncthreads();

  // ---- layer 1: 64 -> 64 (float4 weight loads; FMA order unchanged) ----
  {
    float a1[8];
    float bu = b1[2 * og], bw = b1[2 * og + 1];
    a1[0] = a1[1] = a1[2] = a1[3] = bu;
    a1[4] = a1[5] = a1[6] = a1[7] = bw;
    const float4* wv0 = (const float4*)(w1 + (2 * og) * 64);
    const float4* wv1 = (const float4*)(w1 + (2 * og + 1) * 64);
    for (int c4 = 0; c4 < 16; c4++) {
      float4 u4 = wv0[c4], v4 = wv1[c4];
#pragma unroll
      for (int i = 0; i < 4; i++) {
        int c = c4 * 4 + i;
        float u = (i == 0) ? u4.x : (i == 1) ? u4.y : (i == 2) ? u4.z : u4.w;
        float v = (i == 0) ? v4.x : (i == 1) ? v4.y : (i == 2) ? v4.z : v4.w;
        float4 f = *(const float4*)&h0s[c * 36 + kq * 4];
        a1[0] = fmaf(u, f.x, a1[0]); a1[1] = fmaf(u, f.y, a1[1]);
        a1[2] = fmaf(u, f.z, a1[2]); a1[3] = fmaf(u, f.w, a1[3]);
        a1[4] = fmaf(v, f.x, a1[4]); a1[5] = fmaf(v, f.y, a1[5]);
        a1[6] = fmaf(v, f.z, a1[6]); a1[7] = fmaf(v, f.w, a1[7]);
      }
    }
    float4 r0, r1;
    r0.x = fmaxf(a1[0], 0.f); r0.y = fmaxf(a1[1], 0.f);
    r0.z = fmaxf(a1[2], 0.f); r0.w = fmaxf(a1[3], 0.f);
    r1.x = fmaxf(a1[4], 0.f); r1.y = fmaxf(a1[5], 0.f);
    r1.z = fmaxf(a1[6], 0.f); r1.w = fmaxf(a1[7], 0.f);
    *(float4*)&h1s[(2 * og) * 36 + kq * 4] = r0;
    *(float4*)&h1s[(2 * og + 1) * 36 + kq * 4] = r1;
  }
  __syncthreads();

  // ---- layer 2: 64 -> 128 (float4 weight loads), then max over k ----
  {
    const int kq2 = t & 3;   // k block = 8*kq2 .. +8
    const int og2 = t >> 2;  // o = 2*og2, 2*og2+1
    float a2[16];
    float bu = b2[2 * og2], bw = b2[2 * og2 + 1];
#pragma unroll
    for (int i = 0; i < 8; i++) { a2[i] = bu; a2[8 + i] = bw; }
    const float4* wv0 = (const float4*)(w2 + (2 * og2) * 64);
    const float4* wv1 = (const float4*)(w2 + (2 * og2 + 1) * 64);
    for (int c4 = 0; c4 < 16; c4++) {
      float4 u4 = wv0[c4], v4 = wv1[c4];
#pragma unroll
      for (int i = 0; i < 4; i++) {
        int c = c4 * 4 + i;
        float u = (i == 0) ? u4.x : (i == 1) ? u4.y : (i == 2) ? u4.z : u4.w;
        float v = (i == 0) ? v4.x : (i == 1) ? v4.y : (i == 2) ? v4.z : v4.w;
        float4 fA = *(const float4*)&h1s[c * 36 + kq2 * 8];
        float4 fB = *(const float4*)&h1s[c * 36 + kq2 * 8 + 4];
        a2[0] = fmaf(u, fA.x, a2[0]);  a2[1] = fmaf(u, fA.y, a2[1]);
        a2[2] = fmaf(u, fA.z, a2[2]);  a2[3] = fmaf(u, fA.w, a2[3]);
        a2[4] = fmaf(u, fB.x, a2[4]);  a2[5] = fmaf(u, fB.y, a2[5]);
        a2[6] = fmaf(u, fB.z, a2[6]);  a2[7] = fmaf(u, fB.w, a2[7]);
        a2[8] = fmaf(v, fA.x, a2[8]);  a2[9] = fmaf(v, fA.y, a2[9]);
        a2[10] = fmaf(v, fA.z, a2[10]); a2[11] = fmaf(v, fA.w, a2[11]);
        a2[12] = fmaf(v, fB.x, a2[12]); a2[13] = fmaf(v, fB.y, a2[13]);
        a2[14] = fmaf(v, fB.z, a2[14]); a2[15] = fmaf(v, fB.w, a2[15]);
      }
    }
    // relu then max over k == max then relu (relu is monotone)
    float m0 = a2[0], m1 = a2[8];
#pragma unroll
    for (int i = 1; i < 8; i++) { m0 = fmaxf(m0, a2[i]); m1 = fmaxf(m1, a2[8 + i]); }
    m0 = fmaxf(m0, 0.f);
    m1 = fmaxf(m1, 0.f);
    // reduce over the 4 lanes sharing og2 (kq2 = 0..3, adjacent lanes)
    m0 = fmaxf(m0, __shfl_xor(m0, 1, 64));
    m0 = fmaxf(m0, __shfl_xor(m0, 2, 64));
    m1 = fmaxf(m1, __shfl_xor(m1, 1, 64));
    m1 = fmaxf(m1, __shfl_xor(m1, 2, 64));
    if (kq2 == 0) {
      out_np[((size_t)b * 128 + 2 * og2) * NSAMP + s] = m0;
      out_np[((size_t)b * 128 + 2 * og2 + 1) * NSAMP + s] = m1;
    }
  }
}

extern "C" void kernel_launch(void* const* d_in, const int* in_sizes, int n_in,
                              void* d_out, int out_size, void* d_ws, size_t ws_size,
                              hipStream_t stream) {
  (void)in_sizes; (void)n_in; (void)out_size; (void)d_ws; (void)ws_size;
  const float* xyz = (const float*)d_in[0];
  const float* pts = (const float*)d_in[1];
  const float* att = (const float*)d_in[2];
  const float* w0 = (const float*)d_in[3];
  const float* b0 = (const float*)d_in[4];
  const float* w1 = (const float*)d_in[5];
  const float* b1 = (const float*)d_in[6];
  const float* w2 = (const float*)d_in[7];
  const float* b2 = (const float*)d_in[8];

  float* out = (float*)d_out;
  float* out_newxyz = out;                                           // (B,3,S)
  float* out_newpts = out + NBATCH * 3 * NSAMP;                      // (B,128,S)
  float* out_att = out + NBATCH * 3 * NSAMP + NBATCH * 128 * NSAMP;  // (B,1,S)

  fps_kernel<<<NBATCH, 512, 0, stream>>>(xyz, out_newxyz);
  sample_kernel<<<NBATCH * NSAMP, 256, 0, stream>>>(
      xyz, pts, att, out_newxyz, w0, b0, w1, b1, w2, b2, out_newpts, out_att);
}